// Round 15
// baseline (335.094 us; speedup 1.0000x reference)
//
#include <hip/hip_runtime.h>
#include <hip/hip_bf16.h>
#include <math.h>

// ---- problem constants ----
#define TN 2048
#define BN 2
#define DF 1024
#define DM 512
#define NHD 8
#define DHD 64
#define INV_E 0.36787944117144233f
#define R_DECAY 0.69220062755534635f  // exp(-1/e)

typedef float f32x4 __attribute__((ext_vector_type(4)));
typedef __bf16 bf16x8 __attribute__((ext_vector_type(8)));
typedef unsigned short ushort8 __attribute__((ext_vector_type(8)));
typedef unsigned short ushort4v __attribute__((ext_vector_type(4)));
typedef unsigned int u32x4 __attribute__((ext_vector_type(4)));
typedef unsigned short u16;
typedef unsigned int u32;

__device__ inline u16 f2bf(float f) {
    __hip_bfloat16 b = __float2bfloat16(f);
    return __builtin_bit_cast(u16, b);
}
__device__ inline float bf2f(u16 u) {
    unsigned int x = ((unsigned int)u) << 16;
    return __builtin_bit_cast(float, x);
}
__device__ inline bf16x8 ldbf8(const u16* p) {
    return __builtin_bit_cast(bf16x8, *(const ushort8*)p);
}

// ---- merged weight transpose: 8 weights, src [K][N] f32 -> dst [N][K] bf16 ----
struct WtrAll {
    const float* src[8];
    u16* dst[8];
    int K[8], N[8], start[8], mask[8], shift[8];
};

__global__ __launch_bounds__(256) void wtr_all_kernel(WtrAll a) {
    __shared__ u16 tile[64][67];
    int bid = blockIdx.x;
    int w = 0;
#pragma unroll
    for (int i = 1; i < 8; ++i)
        if (bid >= a.start[i]) w = i;
    const float* src = a.src[w];
    u16* dst = a.dst[w];
    int K = a.K[w], N = a.N[w];
    int t0 = bid - a.start[w];
    int bx = t0 & a.mask[w], by = t0 >> a.shift[w];
    int t = threadIdx.x;
    int tr = t >> 4, tc = (t & 15) * 4;
#pragma unroll
    for (int rr = 0; rr < 4; ++rr) {
        int kl = tr + rr * 16;
        float4 v = *(const float4*)&src[(size_t)(by * 64 + kl) * N + bx * 64 + tc];
        tile[kl][tc + 0] = f2bf(v.x);
        tile[kl][tc + 1] = f2bf(v.y);
        tile[kl][tc + 2] = f2bf(v.z);
        tile[kl][tc + 3] = f2bf(v.w);
    }
    __syncthreads();
#pragma unroll
    for (int rr = 0; rr < 4; ++rr) {
        int nl = tr + rr * 16;
        ushort4v o;
#pragma unroll
        for (int q = 0; q < 4; ++q) o[q] = tile[tc + q][nl];
        *(ushort4v*)&dst[(size_t)(bx * 64 + nl) * K + by * 64 + tc] = o;
    }
}

// emb_w [DM][DF][3] -> [DM][3*DF] bf16 with k = tap*DF + i
__global__ __launch_bounds__(256) void emb_tr_kernel(const float* __restrict__ w,
                                                     u16* __restrict__ dst) {
    int idx = blockIdx.x * 256 + threadIdx.x;
    if (idx >= DM * 3 * DF) return;
    int o = idx / (3 * DF);
    int rem = idx - o * 3 * DF;
    int tap = rem / DF, i = rem - tap * DF;
    dst[idx] = f2bf(w[(size_t)o * 3 * DF + i * 3 + tap]);
}

// sinv[j] = 1 / sum_k r^{|j-k|} (closed-form geometric sums; exact full-range)
__global__ __launch_bounds__(256) void sinv_kernel(float* __restrict__ sinv) {
    int j = blockIdx.x * 256 + threadIdx.x;
    if (j >= TN) return;
    float r = __expf(-INV_E);
    float inv1mr = 1.f / (1.f - r);
    float a = (1.f - __expf(-(float)(j + 1) * INV_E)) * inv1mr;
    float b = (r - __expf(-(float)(TN - j) * INV_E)) * inv1mr;
    sinv[j] = 1.f / (a + b);
}

// ---- pipelined GEMM (reg-staged dbuf) + bijective XCD-chunk swizzle ----
// C[M][N] = epi(A[M][K]bf16 @ Bt[N][K(s)]bf16^T). 1D grid.x (nwg%8==0), N fastest.
// CONVA: split-K conv — A is x [B][T][DF] f32, tap = blockIdx.y, out = f32 partial
//        pc + tap*M*N; B cols tap*1024.. (row stride Ks).
// MODE bits: 1=bias,2=relu,4=gelu,8=+resid(f32),16=f32out
template <int MODE, int BM, int BNT, int LOG_NX, int CONVA>
__global__ __launch_bounds__(256) void gemm2(const u16* __restrict__ A,
                                             const u16* __restrict__ Bt,
                                             const float* __restrict__ bias,
                                             const float* resid, void* outp,
                                             int M, int N, int K, int Ks) {
    constexpr int MR = BM / 32, NR = BNT / 32;
    constexpr int PA = BM / 64, PB = BNT / 64;
    __shared__ __align__(16) u16 As[2][BM][72];
    __shared__ __align__(16) u16 Bs[2][BNT][72];
    int tid = threadIdx.x;
    int lane = tid & 63, wid = tid >> 6;
    int cpx = gridDim.x >> 3;
    int swz = (blockIdx.x & 7) * cpx + (blockIdx.x >> 3);
    int n0 = (swz & ((1 << LOG_NX) - 1)) * BNT;
    int m0 = (swz >> LOG_NX) * BM;
    int tap = CONVA ? blockIdx.y : 0;
    int wm = (wid >> 1) * (BM / 2), wn = (wid & 1) * (BNT / 2);
    int fr = lane & 15, kq = (lane >> 4) * 8;
    int srow = tid >> 2, scol = (tid & 3) * 16;
    f32x4 acc[MR][NR] = {};
    const float* xin = (const float*)A;
    const u16* Ap = A + (size_t)(m0 + srow) * Ks + scol;
    const u16* Bp = Bt + (CONVA ? tap * DF : 0) + (size_t)(n0 + srow) * Ks + scol;
    ushort8 ra[PA][2], rb[PB][2];
    float4 raf[PA][4];

    auto loadA = [&](int k0) {
        if constexpr (CONVA) {
            int acol = k0 + scol;
#pragma unroll
            for (int p = 0; p < PA; ++p) {
                int row = m0 + srow + p * 64;
                int tt = (row & (TN - 1)) + tap - 1;
                if (tt >= 0 && tt < TN) {
                    const float* s = xin + ((size_t)((row >> 11) * TN + tt)) * DF + acol;
#pragma unroll
                    for (int q = 0; q < 4; ++q) raf[p][q] = *(const float4*)(s + q * 4);
                } else {
#pragma unroll
                    for (int q = 0; q < 4; ++q) raf[p][q] = float4{0.f, 0.f, 0.f, 0.f};
                }
            }
        } else {
#pragma unroll
            for (int p = 0; p < PA; ++p) {
                ra[p][0] = *(const ushort8*)(Ap + (size_t)p * 64 * Ks + k0);
                ra[p][1] = *(const ushort8*)(Ap + (size_t)p * 64 * Ks + k0 + 8);
            }
        }
    };
    auto writeA = [&](int pb) {
#pragma unroll
        for (int p = 0; p < PA; ++p) {
            if constexpr (CONVA) {
                ushort8 w0, w1;
#pragma unroll
                for (int q = 0; q < 4; ++q) {
                    w0[q] = f2bf(raf[p][0][q]);
                    w0[4 + q] = f2bf(raf[p][1][q]);
                    w1[q] = f2bf(raf[p][2][q]);
                    w1[4 + q] = f2bf(raf[p][3][q]);
                }
                *(ushort8*)&As[pb][srow + p * 64][scol] = w0;
                *(ushort8*)&As[pb][srow + p * 64][scol + 8] = w1;
            } else {
                *(ushort8*)&As[pb][srow + p * 64][scol] = ra[p][0];
                *(ushort8*)&As[pb][srow + p * 64][scol + 8] = ra[p][1];
            }
        }
    };

    loadA(0);
#pragma unroll
    for (int p = 0; p < PB; ++p) {
        rb[p][0] = *(const ushort8*)(Bp + (size_t)p * 64 * Ks);
        rb[p][1] = *(const ushort8*)(Bp + (size_t)p * 64 * Ks + 8);
    }
    int nt = K >> 6;
    int pb = 0;
    for (int t = 0; t < nt; ++t) {
        writeA(pb);
#pragma unroll
        for (int p = 0; p < PB; ++p) {
            *(ushort8*)&Bs[pb][srow + p * 64][scol] = rb[p][0];
            *(ushort8*)&Bs[pb][srow + p * 64][scol + 8] = rb[p][1];
        }
        __syncthreads();
        if (t + 1 < nt) {
            int ko = (t + 1) << 6;
            loadA(ko);
#pragma unroll
            for (int p = 0; p < PB; ++p) {
                rb[p][0] = *(const ushort8*)(Bp + (size_t)p * 64 * Ks + ko);
                rb[p][1] = *(const ushort8*)(Bp + (size_t)p * 64 * Ks + ko + 8);
            }
        }
#pragma unroll
        for (int kc = 0; kc < 2; ++kc) {
            bf16x8 af[MR], bf[NR];
#pragma unroll
            for (int a = 0; a < MR; ++a) af[a] = ldbf8(&As[pb][wm + a * 16 + fr][kc * 32 + kq]);
#pragma unroll
            for (int b = 0; b < NR; ++b) bf[b] = ldbf8(&Bs[pb][wn + b * 16 + fr][kc * 32 + kq]);
#pragma unroll
            for (int a = 0; a < MR; ++a)
#pragma unroll
                for (int b = 0; b < NR; ++b)
                    acc[a][b] = __builtin_amdgcn_mfma_f32_16x16x32_bf16(af[a], bf[b], acc[a][b], 0, 0, 0);
        }
        pb ^= 1;
    }
    int rq = (lane >> 4) * 4;
    float* outc = (float*)outp;
    if constexpr (CONVA) outc += (size_t)tap * M * N;
#pragma unroll
    for (int a = 0; a < MR; ++a)
#pragma unroll
        for (int b = 0; b < NR; ++b) {
            int col = n0 + wn + b * 16 + fr;
            float bv = (MODE & 1) ? bias[col] : 0.f;
#pragma unroll
            for (int r = 0; r < 4; ++r) {
                int row = m0 + wm + a * 16 + rq + r;
                float v = acc[a][b][r] + bv;
                if (MODE & 2) v = fmaxf(v, 0.f);
                if (MODE & 4) v = 0.5f * v * (1.f + erff(v * 0.7071067811865476f));
                if (MODE & 8) v += resid[(size_t)row * N + col];
                if (MODE & 16) outc[(size_t)row * N + col] = v;
                else           ((u16*)outp)[(size_t)row * N + col] = f2bf(v);
            }
        }
}

// ---- conv split-K combine: h = relu(p0 + p1 + p2 + bias) ----
__global__ __launch_bounds__(256) void conv_combine_kernel(const float* __restrict__ pc,
                                                           const float* __restrict__ bias,
                                                           float* __restrict__ h) {
    int idx = blockIdx.x * 256 + threadIdx.x;  // per float4; total M*N/4 = 524288
    const size_t PS = (size_t)BN * TN * DM;
    float4 p0 = *(const float4*)(pc + (size_t)idx * 4);
    float4 p1 = *(const float4*)(pc + PS + (size_t)idx * 4);
    float4 p2 = *(const float4*)(pc + 2 * PS + (size_t)idx * 4);
    float4 bv = *(const float4*)(bias + (idx & (DM / 4 - 1)) * 4);
    float4 o;
    o.x = fmaxf(p0.x + p1.x + p2.x + bv.x, 0.f);
    o.y = fmaxf(p0.y + p1.y + p2.y + bv.y, 0.f);
    o.z = fmaxf(p0.z + p1.z + p2.z + bv.z, 0.f);
    o.w = fmaxf(p0.w + p1.w + p2.w + bv.w, 0.f);
    *(float4*)(h + (size_t)idx * 4) = o;
}

// ---- LayerNorm: h[row][512] fp32 -> bf16 ----
__global__ __launch_bounds__(256) void ln_kernel(const float* __restrict__ h,
                                                 const float* __restrict__ g,
                                                 const float* __restrict__ bta,
                                                 u16* __restrict__ outp) {
    int lane = threadIdx.x & 63, wid = threadIdx.x >> 6;
    int row = blockIdx.x * 4 + wid;
    const float4* xp = (const float4*)(h + (size_t)row * DM + lane * 8);
    float4 v0 = xp[0], v1 = xp[1];
    float v[8] = {v0.x, v0.y, v0.z, v0.w, v1.x, v1.y, v1.z, v1.w};
    float s = 0.f;
#pragma unroll
    for (int i = 0; i < 8; ++i) s += v[i];
    for (int sft = 1; sft < 64; sft <<= 1) s += __shfl_xor(s, sft, 64);
    float mean = s * (1.f / DM);
    float q = 0.f;
#pragma unroll
    for (int i = 0; i < 8; ++i) { float d = v[i] - mean; q += d * d; }
    for (int sft = 1; sft < 64; sft <<= 1) q += __shfl_xor(q, sft, 64);
    float rs = rsqrtf(q * (1.f / DM) + 1e-5f);
    ushort8 o;
#pragma unroll
    for (int i = 0; i < 8; ++i) {
        float y = (v[i] - mean) * rs * g[lane * 8 + i] + bta[lane * 8 + i];
        o[i] = f2bf(y);
    }
    *(ushort8*)&outp[(size_t)row * DM + lane * 8] = o;
}

// ---- flash attention v7: 4 KV-chunks of 512 keys, grid 1024,
//      32 q-rows per wave (2 slices share each K/V LDS read) ----
__global__ __launch_bounds__(256, 4) void attn_split(const u16* __restrict__ qkvt,
                                                     u16* __restrict__ po,
                                                     float* __restrict__ pl) {
    __shared__ __align__(16) u16 Ks[64][72];
    __shared__ __align__(16) u16 Vs[64][72];
    int tid = threadIdx.x;
    int lane = tid & 63, wid = tid >> 6;
    int bid = blockIdx.x;
    int cc = bid & 3, qb = (bid >> 2) & 15, hh = (bid >> 6) & 7, b = bid >> 9;
    int fr = lane & 15, kq = (lane >> 4) * 8, rq = (lane >> 4) * 4;

    bf16x8 aq[2][2];
#pragma unroll
    for (int s = 0; s < 2; ++s)
#pragma unroll
        for (int kc = 0; kc < 2; ++kc) {
            int qrow = qb * 128 + wid * 32 + s * 16 + fr;
            bf16x8 t = ldbf8(&qkvt[((size_t)(b * TN + qrow)) * 2048 + hh * 64 + kc * 32 + kq]);
            bf16x8 sc;
#pragma unroll
            for (int i = 0; i < 8; ++i) sc[i] = (__bf16)(0.125f * (float)t[i]);
            aq[s][kc] = sc;
        }

    f32x4 o[2][4] = {};
    float rsum[2] = {0.f, 0.f};

    int srow = tid >> 3, scol = (tid & 7) * 8;
    int vxw = ((scol >> 3) & 7) << 3;
    int i01 = (fr + ((lane & 16) << 1)) << 2;
    int i23 = i01 + 64;
    bool hi2 = (lane & 32) != 0;

    const u16* kvbase = qkvt + ((size_t)(b * TN + cc * 512 + srow)) * 2048 + hh * 64 + scol;

    ushort8 rk[2], rv[2];
    rk[0] = *(const ushort8*)(kvbase + 512);
    rk[1] = *(const ushort8*)(kvbase + 512 + (size_t)32 * 2048);
    rv[0] = *(const ushort8*)(kvbase + 1024);
    rv[1] = *(const ushort8*)(kvbase + 1024 + (size_t)32 * 2048);

    for (int t = 0; t < 8; ++t) {
        __syncthreads();
#pragma unroll
        for (int half = 0; half < 2; ++half) {
            int jr = srow + half * 32;
            *(ushort8*)&Ks[jr][scol] = rk[half];
            int jc = jr ^ vxw;
#pragma unroll
            for (int i = 0; i < 8; ++i) Vs[scol + i][jc] = rv[half][i];
        }
        __syncthreads();
        if (t < 7) {
            const u16* kb2 = kvbase + (size_t)(t + 1) * 64 * 2048;
            rk[0] = *(const ushort8*)(kb2 + 512);
            rk[1] = *(const ushort8*)(kb2 + 512 + (size_t)32 * 2048);
            rv[0] = *(const ushort8*)(kb2 + 1024);
            rv[1] = *(const ushort8*)(kb2 + 1024 + (size_t)32 * 2048);
        }
        u32 pkr[2][4][2];
#pragma unroll
        for (int jb = 0; jb < 4; ++jb) {
            f32x4 sa0 = f32x4{0.f, 0.f, 0.f, 0.f};
            f32x4 sa1 = f32x4{0.f, 0.f, 0.f, 0.f};
#pragma unroll
            for (int kc = 0; kc < 2; ++kc) {
                bf16x8 bk = ldbf8(&Ks[jb * 16 + fr][kc * 32 + kq]);
                sa0 = __builtin_amdgcn_mfma_f32_16x16x32_bf16(bk, aq[0][kc], sa0, 0, 0, 0);
                sa1 = __builtin_amdgcn_mfma_f32_16x16x32_bf16(bk, aq[1][kc], sa1, 0, 0, 0);
            }
            {
                float p0 = __expf(sa0[0]), p1 = __expf(sa0[1]);
                float p2 = __expf(sa0[2]), p3 = __expf(sa0[3]);
                rsum[0] += (p0 + p1) + (p2 + p3);
                pkr[0][jb][0] = ((u32)f2bf(p1) << 16) | (u32)f2bf(p0);
                pkr[0][jb][1] = ((u32)f2bf(p3) << 16) | (u32)f2bf(p2);
            }
            {
                float p0 = __expf(sa1[0]), p1 = __expf(sa1[1]);
                float p2 = __expf(sa1[2]), p3 = __expf(sa1[3]);
                rsum[1] += (p0 + p1) + (p2 + p3);
                pkr[1][jb][0] = ((u32)f2bf(p1) << 16) | (u32)f2bf(p0);
                pkr[1][jb][1] = ((u32)f2bf(p3) << 16) | (u32)f2bf(p2);
            }
        }
        bf16x8 pa[2][2];
#pragma unroll
        for (int s = 0; s < 2; ++s)
#pragma unroll
            for (int kc = 0; kc < 2; ++kc) {
                u32 a0 = (u32)__builtin_amdgcn_ds_bpermute(i01, (int)pkr[s][kc * 2][0]);
                u32 b0 = (u32)__builtin_amdgcn_ds_bpermute(i01, (int)pkr[s][kc * 2 + 1][0]);
                u32 a1 = (u32)__builtin_amdgcn_ds_bpermute(i01, (int)pkr[s][kc * 2][1]);
                u32 b1 = (u32)__builtin_amdgcn_ds_bpermute(i01, (int)pkr[s][kc * 2 + 1][1]);
                u32 a2 = (u32)__builtin_amdgcn_ds_bpermute(i23, (int)pkr[s][kc * 2][0]);
                u32 b2 = (u32)__builtin_amdgcn_ds_bpermute(i23, (int)pkr[s][kc * 2 + 1][0]);
                u32 a3 = (u32)__builtin_amdgcn_ds_bpermute(i23, (int)pkr[s][kc * 2][1]);
                u32 b3 = (u32)__builtin_amdgcn_ds_bpermute(i23, (int)pkr[s][kc * 2 + 1][1]);
                u32x4 w;
                w[0] = hi2 ? b0 : a0;
                w[1] = hi2 ? b1 : a1;
                w[2] = hi2 ? b2 : a2;
                w[3] = hi2 ? b3 : a3;
                pa[s][kc] = __builtin_bit_cast(bf16x8, w);
            }
#pragma unroll
        for (int cb = 0; cb < 4; ++cb)
#pragma unroll
            for (int kc = 0; kc < 2; ++kc) {
                int vrow = cb * 16 + fr;
                bf16x8 bv = ldbf8(&Vs[vrow][(kc * 32 + kq) ^ (((vrow >> 3) & 7) << 3)]);
                o[0][cb] = __builtin_amdgcn_mfma_f32_16x16x32_bf16(pa[0][kc], bv, o[0][cb], 0, 0, 0);
                o[1][cb] = __builtin_amdgcn_mfma_f32_16x16x32_bf16(pa[1][kc], bv, o[1][cb], 0, 0, 0);
            }
    }
#pragma unroll
    for (int s = 0; s < 2; ++s) {
        rsum[s] += __shfl_xor(rsum[s], 16, 64);
        rsum[s] += __shfl_xor(rsum[s], 32, 64);
    }
#pragma unroll
    for (int s = 0; s < 2; ++s)
#pragma unroll
        for (int r = 0; r < 4; ++r) {
            int grow = (b * NHD + hh) * TN + qb * 128 + wid * 32 + s * 16 + rq + r;
            size_t pidx = (size_t)grow * 4 + cc;
#pragma unroll
            for (int cb = 0; cb < 4; ++cb)
                po[pidx * 64 + cb * 16 + fr] = f2bf(o[s][cb][r]);
        }
    if (lane < 16) {
#pragma unroll
        for (int s = 0; s < 2; ++s) {
            int grow = (b * NHD + hh) * TN + qb * 128 + wid * 32 + s * 16 + fr;
            pl[(size_t)grow * 4 + cc] = rsum[s];
        }
    }
}

// ---- merged post-attention: combine 4 partials (blocks 0..2047) + decay scan ----
#define BCH 32
__global__ __launch_bounds__(256) void postattn_kernel(const u16* __restrict__ po,
                                                       const float* __restrict__ pl,
                                                       const u16* __restrict__ qkvt,
                                                       const float* __restrict__ sinv,
                                                       u16* __restrict__ attcat) {
    int bid = blockIdx.x;
    if (bid < BN * NHD * TN / 4) {
        int lane = threadIdx.x & 63, wid = threadIdx.x >> 6;
        int R = bid * 4 + wid;
        float l = 0.f, ov = 0.f;
#pragma unroll
        for (int cc = 0; cc < 4; ++cc) {
            l += pl[(size_t)R * 4 + cc];
            ov += bf2f(po[((size_t)R * 4 + cc) * 64 + lane]);
        }
        int bh = R >> 11, q = R & (TN - 1);
        int b = bh >> 3, hh = bh & 7;
        attcat[((size_t)(b * TN + q)) * 1024 + hh * 128 + lane] = f2bf(ov / l);
    } else {
        int t2 = (bid - BN * NHD * TN / 4) * 256 + threadIdx.x;
        int c = t2 & 511;
        int rest = t2 >> 9;
        int chunk = rest & 63;
        int b = rest >> 6;
        int i0 = chunk * BCH;
        const float r = R_DECAY;
        const u16* tcol = qkvt + 1536 + c;
        float regs[BCH];
        float st = 0.f;
        for (int j = i0 - 32; j < i0; ++j) {
            if (j >= 0) st = r * st + sinv[j] * bf2f(tcol[(size_t)(b * TN + j) * 2048]);
        }
#pragma unroll
        for (int k = 0; k < BCH; ++k) {
            int j = i0 + k;
            st = r * st + sinv[j] * bf2f(tcol[(size_t)(b * TN + j) * 2048]);
            regs[k] = st;
        }
        st = 0.f;
        for (int j = i0 + BCH + 31; j >= i0 + BCH; --j) {
            if (j < TN) st = r * st + sinv[j] * bf2f(tcol[(size_t)(b * TN + j) * 2048]);
        }
#pragma unroll
        for (int k = BCH - 1; k >= 0; --k) {
            int j = i0 + k;
            regs[k] += r * st;
            st = r * st + sinv[j] * bf2f(tcol[(size_t)(b * TN + j) * 2048]);
        }
        int outcol = (c >> 6) * 128 + 64 + (c & 63);
#pragma unroll
        for (int k = 0; k < BCH; ++k)
            attcat[((size_t)(b * TN + i0 + k)) * 1024 + outcol] = f2bf(regs[k]);
    }
}

// ---- fused head ----
__global__ __launch_bounds__(256) void head_kernel(
    const float* __restrict__ h, const float* __restrict__ h1w, const float* __restrict__ h1b,
    const float* __restrict__ bn1g, const float* __restrict__ bn1b,
    const float* __restrict__ bn1m, const float* __restrict__ bn1v,
    const float* __restrict__ h2w, const float* __restrict__ h2b,
    const float* __restrict__ bn2g, const float* __restrict__ bn2b,
    const float* __restrict__ bn2m, const float* __restrict__ bn2v,
    const float* __restrict__ h3w, const float* __restrict__ h3b,
    float* __restrict__ outp) {
    int lane = threadIdx.x & 63, wid = threadIdx.x >> 6;
    int idx = blockIdx.x * 4 + wid;
    const float4* xp = (const float4*)(h + (size_t)idx * DM + lane * 8);
    float4 v0 = xp[0], v1 = xp[1];
    float v[8] = {v0.x, v0.y, v0.z, v0.w, v1.x, v1.y, v1.z, v1.w};
    float a1[32];
#pragma unroll
    for (int o = 0; o < 32; ++o) {
        const float4* wp = (const float4*)(h1w + (size_t)o * DM + lane * 8);
        float4 w0 = wp[0], w1v = wp[1];
        a1[o] = w0.x * v[0] + w0.y * v[1] + w0.z * v[2] + w0.w * v[3] +
                w1v.x * v[4] + w1v.y * v[5] + w1v.z * v[6] + w1v.w * v[7];
    }
    for (int sft = 1; sft < 64; sft <<= 1) {
#pragma unroll
        for (int o = 0; o < 32; ++o) a1[o] += __shfl_xor(a1[o], sft, 64);
    }
    float r1[32];
#pragma unroll
    for (int o = 0; o < 32; ++o) {
        float f = a1[o] + h1b[o];
        f = (f - bn1m[o]) * rsqrtf(bn1v[o] + 1e-5f) * bn1g[o] + bn1b[o];
        r1[o] = fmaxf(f, 0.f);
    }
    float r2[16];
#pragma unroll
    for (int p = 0; p < 16; ++p) {
        float s = h2b[p];
#pragma unroll
        for (int o = 0; o < 32; ++o) s = fmaf(h2w[p * 32 + o], r1[o], s);
        s = (s - bn2m[p]) * rsqrtf(bn2v[p] + 1e-5f) * bn2g[p] + bn2b[p];
        r2[p] = fmaxf(s, 0.f);
    }
    float f3 = h3b[0];
#pragma unroll
    for (int p = 0; p < 16; ++p) f3 = fmaf(h3w[p], r2[p], f3);
    if (lane == 0) outp[idx] = 1.f / (1.f + __expf(-f3));
}

extern "C" void kernel_launch(void* const* d_in, const int* in_sizes, int n_in,
                              void* d_out, int out_size, void* d_ws, size_t ws_size,
                              hipStream_t stream) {
    const float* x     = (const float*)d_in[0];
    const float* emb_w = (const float*)d_in[1];
    const float* emb_b = (const float*)d_in[2];
    const float* ln1_g = (const float*)d_in[3];
    const float* ln1_b = (const float*)d_in[4];
    const float* wqkvt = (const float*)d_in[5];
    const float* wout  = (const float*)d_in[6];
    const float* bout  = (const float*)d_in[7];
    const float* ln2_g = (const float*)d_in[8];
    const float* ln2_b = (const float*)d_in[9];
    const float* w1    = (const float*)d_in[10];
    const float* b1    = (const float*)d_in[11];
    const float* w2    = (const float*)d_in[12];
    const float* b2    = (const float*)d_in[13];
    const float* h1w   = (const float*)d_in[14];
    const float* h1b   = (const float*)d_in[15];
    const float* bn1g  = (const float*)d_in[16];
    const float* bn1b  = (const float*)d_in[17];
    const float* bn1m  = (const float*)d_in[18];
    const float* bn1v  = (const float*)d_in[19];
    const float* h2w   = (const float*)d_in[20];
    const float* h2b   = (const float*)d_in[21];
    const float* bn2g  = (const float*)d_in[22];
    const float* bn2b  = (const float*)d_in[23];
    const float* bn2m  = (const float*)d_in[24];
    const float* bn2v  = (const float*)d_in[25];
    const float* h3w   = (const float*)d_in[26];
    const float* h3b   = (const float*)d_in[27];
    float* outp = (float*)d_out;

    char* ws = (char*)d_ws;
    size_t off = 0;
    auto take = [&](size_t bytes) {
        char* p = ws + off;
        off = (off + bytes + 255) & ~(size_t)255;
        return p;
    };
    const size_t MB = 1024 * 1024;
    float* h    = (float*)take((size_t)BN * TN * DM * 4);   // 8 MB
    char* Pr    = take(25 * MB);                             // union: {pc} | {xln,z1} | {pl,po}
    u16* attcat = (u16*)take((size_t)BN * TN * 1024 * 2);   // 8 MB
    float* sinv = (float*)take(TN * 4);
    u16* embwt  = (u16*)take((size_t)DM * 3 * DF * 2);
    u16* wqt    = (u16*)take((size_t)2 * 2048 * DM * 2);
    u16* woutt  = (u16*)take((size_t)2 * DM * 1024 * 2);
    u16* w1t    = (u16*)take((size_t)2 * DM * DM * 2);
    u16* w2t    = (u16*)take((size_t)2 * DM * DM * 2);
    u16* qkvtb  = (u16*)take((size_t)BN * TN * 2048 * 2);   // 16 MB
    // phase-disjoint aliases inside Pr:
    float* pc = (float*)Pr;           // 24 MB (conv phase only)
    u16* xln  = (u16*)Pr;             // 4 MB (LN phase; dead during attention)
    u16* z1   = (u16*)(Pr + 4 * MB);  // 4 MB (MLP phase; po dead then)
    float* pl = (float*)Pr;           // 512 KB (attention phase only)
    u16* po   = (u16*)(Pr + 1 * MB);  // 16.8 MB (attention phase only)
    (void)ws_size; (void)in_sizes; (void)n_in; (void)out_size;

    emb_tr_kernel<<<dim3(DM * 3 * DF / 256), dim3(256), 0, stream>>>(emb_w, embwt);
    {
        WtrAll a;
        int cur = 0;
        for (int l = 0; l < 2; ++l) {
            int e = l * 4;
            a.src[e + 0] = wqkvt + (size_t)l * 512 * 2048; a.dst[e + 0] = wqt + (size_t)l * 2048 * 512;
            a.K[e + 0] = 512;  a.N[e + 0] = 2048; a.start[e + 0] = cur; a.mask[e + 0] = 31; a.shift[e + 0] = 5; cur += 256;
            a.src[e + 1] = wout + (size_t)l * 1024 * 512;  a.dst[e + 1] = woutt + (size_t)l * 512 * 1024;
            a.K[e + 1] = 1024; a.N[e + 1] = 512;  a.start[e + 1] = cur; a.mask[e + 1] = 7;  a.shift[e + 1] = 3; cur += 128;
            a.src[e + 2] = w1 + (size_t)l * 512 * 512;     a.dst[e + 2] = w1t + (size_t)l * 512 * 512;
            a.K[e + 2] = 512;  a.N[e + 2] = 512;  a.start[e + 2] = cur; a.mask[e + 2] = 7;  a.shift[e + 2] = 3; cur += 64;
            a.src[e + 3] = w2 + (size_t)l * 512 * 512;     a.dst[e + 3] = w2t + (size_t)l * 512 * 512;
            a.K[e + 3] = 512;  a.N[e + 3] = 512;  a.start[e + 3] = cur; a.mask[e + 3] = 7;  a.shift[e + 3] = 3; cur += 64;
        }
        wtr_all_kernel<<<dim3(cur), dim3(256), 0, stream>>>(a);
    }
    sinv_kernel<<<dim3(TN / 256), dim3(256), 0, stream>>>(sinv);

    // conv-as-GEMM split-K by tap: grid (512, 3), f32 partials -> combine
    gemm2<16, 64, 64, 3, 1><<<dim3((DM / 64) * (BN * TN / 64), 3), dim3(256), 0, stream>>>(
        (const u16*)x, embwt, nullptr, nullptr, pc, BN * TN, DM, 1024, 3 * DF);
    conv_combine_kernel<<<dim3(BN * TN * DM / 4 / 256), dim3(256), 0, stream>>>(pc, emb_b, h);

    for (int l = 0; l < 2; ++l) {
        ln_kernel<<<dim3(BN * TN / 4), dim3(256), 0, stream>>>(h, ln1_g + l * DM, ln1_b + l * DM, xln);
        gemm2<0, 128, 128, 4, 0><<<dim3((2048 / 128) * (BN * TN / 128)), dim3(256), 0, stream>>>(
            xln, wqt + (size_t)l * 2048 * 512, nullptr, nullptr, qkvtb, BN * TN, 2048, DM, DM);
        attn_split<<<dim3(BN * NHD * (TN / 128) * 4), dim3(256), 0, stream>>>(qkvtb, po, pl);
        postattn_kernel<<<dim3(BN * NHD * TN / 4 + BN * 512 * (TN / BCH) / 256), dim3(256), 0, stream>>>(
            po, pl, qkvtb, sinv, attcat);
        gemm2<25, 64, 64, 3, 0><<<dim3((DM / 64) * (BN * TN / 64)), dim3(256), 0, stream>>>(
            attcat, woutt + (size_t)l * 512 * 1024, bout + l * DM, h, h, BN * TN, DM, 1024, 1024);
        ln_kernel<<<dim3(BN * TN / 4), dim3(256), 0, stream>>>(h, ln2_g + l * DM, ln2_b + l * DM, xln);
        gemm2<5, 64, 64, 3, 0><<<dim3((DM / 64) * (BN * TN / 64)), dim3(256), 0, stream>>>(
            xln, w1t + (size_t)l * 512 * 512, b1 + l * DM, nullptr, z1, BN * TN, DM, DM, DM);
        gemm2<25, 64, 64, 3, 0><<<dim3((DM / 64) * (BN * TN / 64)), dim3(256), 0, stream>>>(
            z1, w2t + (size_t)l * 512 * 512, b2 + l * DM, h, h, BN * TN, DM, DM, DM);
    }
    head_kernel<<<dim3(BN * TN / 4), dim3(256), 0, stream>>>(
        h, h1w, h1b, bn1g, bn1b, bn1m, bn1v, h2w, h2b, bn2g, bn2b, bn2m, bn2v, h3w, h3b, outp);
}

// Round 16
// 322.237 us; speedup vs baseline: 1.0399x; 1.0399x over previous
//
#include <hip/hip_runtime.h>
#include <hip/hip_bf16.h>
#include <math.h>

// ---- problem constants ----
#define TN 2048
#define BN 2
#define DF 1024
#define DM 512
#define NHD 8
#define DHD 64
#define INV_E 0.36787944117144233f
#define R_DECAY 0.69220062755534635f  // exp(-1/e)

typedef float f32x4 __attribute__((ext_vector_type(4)));
typedef __bf16 bf16x8 __attribute__((ext_vector_type(8)));
typedef unsigned short ushort8 __attribute__((ext_vector_type(8)));
typedef unsigned short ushort4v __attribute__((ext_vector_type(4)));
typedef unsigned int u32x4 __attribute__((ext_vector_type(4)));
typedef unsigned short u16;
typedef unsigned int u32;

__device__ inline u16 f2bf(float f) {
    __hip_bfloat16 b = __float2bfloat16(f);
    return __builtin_bit_cast(u16, b);
}
__device__ inline float bf2f(u16 u) {
    unsigned int x = ((unsigned int)u) << 16;
    return __builtin_bit_cast(float, x);
}
__device__ inline bf16x8 ldbf8(const u16* p) {
    return __builtin_bit_cast(bf16x8, *(const ushort8*)p);
}

// ---- merged weight transpose: 8 weights, src [K][N] f32 -> dst [N][K] bf16 ----
struct WtrAll {
    const float* src[8];
    u16* dst[8];
    int K[8], N[8], start[8], mask[8], shift[8];
};

__global__ __launch_bounds__(256) void wtr_all_kernel(WtrAll a) {
    __shared__ u16 tile[64][67];
    int bid = blockIdx.x;
    int w = 0;
#pragma unroll
    for (int i = 1; i < 8; ++i)
        if (bid >= a.start[i]) w = i;
    const float* src = a.src[w];
    u16* dst = a.dst[w];
    int K = a.K[w], N = a.N[w];
    int t0 = bid - a.start[w];
    int bx = t0 & a.mask[w], by = t0 >> a.shift[w];
    int t = threadIdx.x;
    int tr = t >> 4, tc = (t & 15) * 4;
#pragma unroll
    for (int rr = 0; rr < 4; ++rr) {
        int kl = tr + rr * 16;
        float4 v = *(const float4*)&src[(size_t)(by * 64 + kl) * N + bx * 64 + tc];
        tile[kl][tc + 0] = f2bf(v.x);
        tile[kl][tc + 1] = f2bf(v.y);
        tile[kl][tc + 2] = f2bf(v.z);
        tile[kl][tc + 3] = f2bf(v.w);
    }
    __syncthreads();
#pragma unroll
    for (int rr = 0; rr < 4; ++rr) {
        int nl = tr + rr * 16;
        ushort4v o;
#pragma unroll
        for (int q = 0; q < 4; ++q) o[q] = tile[tc + q][nl];
        *(ushort4v*)&dst[(size_t)(bx * 64 + nl) * K + by * 64 + tc] = o;
    }
}

// emb_w [DM][DF][3] -> [DM][3*DF] bf16 with k = tap*DF + i; blocks 0-7 also fill sinv
__global__ __launch_bounds__(256) void emb_tr_kernel(const float* __restrict__ w,
                                                     u16* __restrict__ dst,
                                                     float* __restrict__ sinv) {
    int idx = blockIdx.x * 256 + threadIdx.x;
    if (idx < TN) {
        float r = __expf(-INV_E);
        float inv1mr = 1.f / (1.f - r);
        float a = (1.f - __expf(-(float)(idx + 1) * INV_E)) * inv1mr;
        float b = (r - __expf(-(float)(TN - idx) * INV_E)) * inv1mr;
        sinv[idx] = 1.f / (a + b);
    }
    if (idx >= DM * 3 * DF) return;
    int o = idx / (3 * DF);
    int rem = idx - o * 3 * DF;
    int tap = rem / DF, i = rem - tap * DF;
    dst[idx] = f2bf(w[(size_t)o * 3 * DF + i * 3 + tap]);
}

// ---- pipelined GEMM (reg-staged dbuf) + bijective XCD-chunk swizzle ----
// C[M][N] = epi(A[M][K]bf16 @ Bt[N][K]bf16^T). 1D grid (nwg%8==0), N-tiles fastest.
// CONVA: A is x [B][T][DF] f32; A[row][k] = x[b][t + k/DF - 1][k%DF] (0-pad rows).
// MODE bits: 1=bias,2=relu,4=gelu,8=+resid(f32),16=f32out
template <int MODE, int BM, int BNT, int LOG_NX, int CONVA>
__global__ __launch_bounds__(256) void gemm2(const u16* __restrict__ A,
                                             const u16* __restrict__ Bt,
                                             const float* __restrict__ bias,
                                             const float* resid, void* outp,
                                             int M, int N, int K) {
    constexpr int MR = BM / 32, NR = BNT / 32;
    constexpr int PA = BM / 64, PB = BNT / 64;
    __shared__ __align__(16) u16 As[2][BM][72];
    __shared__ __align__(16) u16 Bs[2][BNT][72];
    int tid = threadIdx.x;
    int lane = tid & 63, wid = tid >> 6;
    int cpx = gridDim.x >> 3;
    int swz = (blockIdx.x & 7) * cpx + (blockIdx.x >> 3);
    int n0 = (swz & ((1 << LOG_NX) - 1)) * BNT;
    int m0 = (swz >> LOG_NX) * BM;
    int wm = (wid >> 1) * (BM / 2), wn = (wid & 1) * (BNT / 2);
    int fr = lane & 15, kq = (lane >> 4) * 8;
    int srow = tid >> 2, scol = (tid & 3) * 16;
    f32x4 acc[MR][NR] = {};
    const float* xin = (const float*)A;
    const u16* Ap = A + (size_t)(m0 + srow) * K + scol;
    const u16* Bp = Bt + (size_t)(n0 + srow) * K + scol;
    ushort8 ra[PA][2], rb[PB][2];
    float4 raf[PA][4];

    auto loadA = [&](int k0) {
        if constexpr (CONVA) {
            int tap = k0 >> 10;
            int acol = (k0 & 1023) + scol;
#pragma unroll
            for (int p = 0; p < PA; ++p) {
                int row = m0 + srow + p * 64;
                int tt = (row & (TN - 1)) + tap - 1;
                if (tt >= 0 && tt < TN) {
                    const float* s = xin + ((size_t)((row >> 11) * TN + tt)) * DF + acol;
#pragma unroll
                    for (int q = 0; q < 4; ++q) raf[p][q] = *(const float4*)(s + q * 4);
                } else {
#pragma unroll
                    for (int q = 0; q < 4; ++q) raf[p][q] = float4{0.f, 0.f, 0.f, 0.f};
                }
            }
        } else {
#pragma unroll
            for (int p = 0; p < PA; ++p) {
                ra[p][0] = *(const ushort8*)(Ap + (size_t)p * 64 * K + k0);
                ra[p][1] = *(const ushort8*)(Ap + (size_t)p * 64 * K + k0 + 8);
            }
        }
    };
    auto writeA = [&](int pb) {
#pragma unroll
        for (int p = 0; p < PA; ++p) {
            if constexpr (CONVA) {
                ushort8 w0, w1;
#pragma unroll
                for (int q = 0; q < 4; ++q) {
                    w0[q] = f2bf(raf[p][0][q]);
                    w0[4 + q] = f2bf(raf[p][1][q]);
                    w1[q] = f2bf(raf[p][2][q]);
                    w1[4 + q] = f2bf(raf[p][3][q]);
                }
                *(ushort8*)&As[pb][srow + p * 64][scol] = w0;
                *(ushort8*)&As[pb][srow + p * 64][scol + 8] = w1;
            } else {
                *(ushort8*)&As[pb][srow + p * 64][scol] = ra[p][0];
                *(ushort8*)&As[pb][srow + p * 64][scol + 8] = ra[p][1];
            }
        }
    };

    loadA(0);
#pragma unroll
    for (int p = 0; p < PB; ++p) {
        rb[p][0] = *(const ushort8*)(Bp + (size_t)p * 64 * K);
        rb[p][1] = *(const ushort8*)(Bp + (size_t)p * 64 * K + 8);
    }
    int nt = K >> 6;
    int pb = 0;
    for (int t = 0; t < nt; ++t) {
        writeA(pb);
#pragma unroll
        for (int p = 0; p < PB; ++p) {
            *(ushort8*)&Bs[pb][srow + p * 64][scol] = rb[p][0];
            *(ushort8*)&Bs[pb][srow + p * 64][scol + 8] = rb[p][1];
        }
        __syncthreads();
        if (t + 1 < nt) {
            int ko = (t + 1) << 6;
            loadA(ko);
#pragma unroll
            for (int p = 0; p < PB; ++p) {
                rb[p][0] = *(const ushort8*)(Bp + (size_t)p * 64 * K + ko);
                rb[p][1] = *(const ushort8*)(Bp + (size_t)p * 64 * K + ko + 8);
            }
        }
#pragma unroll
        for (int kc = 0; kc < 2; ++kc) {
            bf16x8 af[MR], bf[NR];
#pragma unroll
            for (int a = 0; a < MR; ++a) af[a] = ldbf8(&As[pb][wm + a * 16 + fr][kc * 32 + kq]);
#pragma unroll
            for (int b = 0; b < NR; ++b) bf[b] = ldbf8(&Bs[pb][wn + b * 16 + fr][kc * 32 + kq]);
#pragma unroll
            for (int a = 0; a < MR; ++a)
#pragma unroll
                for (int b = 0; b < NR; ++b)
                    acc[a][b] = __builtin_amdgcn_mfma_f32_16x16x32_bf16(af[a], bf[b], acc[a][b], 0, 0, 0);
        }
        pb ^= 1;
    }
    int rq = (lane >> 4) * 4;
#pragma unroll
    for (int a = 0; a < MR; ++a)
#pragma unroll
        for (int b = 0; b < NR; ++b) {
            int col = n0 + wn + b * 16 + fr;
            float bv = (MODE & 1) ? bias[col] : 0.f;
#pragma unroll
            for (int r = 0; r < 4; ++r) {
                int row = m0 + wm + a * 16 + rq + r;
                float v = acc[a][b][r] + bv;
                if (MODE & 2) v = fmaxf(v, 0.f);
                if (MODE & 4) v = 0.5f * v * (1.f + erff(v * 0.7071067811865476f));
                if (MODE & 8) v += resid[(size_t)row * N + col];
                if (MODE & 16) ((float*)outp)[(size_t)row * N + col] = v;
                else           ((u16*)outp)[(size_t)row * N + col] = f2bf(v);
            }
        }
}

// ---- LayerNorm: h[row][512] fp32 -> bf16 ----
__global__ __launch_bounds__(256) void ln_kernel(const float* __restrict__ h,
                                                 const float* __restrict__ g,
                                                 const float* __restrict__ bta,
                                                 u16* __restrict__ outp) {
    int lane = threadIdx.x & 63, wid = threadIdx.x >> 6;
    int row = blockIdx.x * 4 + wid;
    const float4* xp = (const float4*)(h + (size_t)row * DM + lane * 8);
    float4 v0 = xp[0], v1 = xp[1];
    float v[8] = {v0.x, v0.y, v0.z, v0.w, v1.x, v1.y, v1.z, v1.w};
    float s = 0.f;
#pragma unroll
    for (int i = 0; i < 8; ++i) s += v[i];
    for (int sft = 1; sft < 64; sft <<= 1) s += __shfl_xor(s, sft, 64);
    float mean = s * (1.f / DM);
    float q = 0.f;
#pragma unroll
    for (int i = 0; i < 8; ++i) { float d = v[i] - mean; q += d * d; }
    for (int sft = 1; sft < 64; sft <<= 1) q += __shfl_xor(q, sft, 64);
    float rs = rsqrtf(q * (1.f / DM) + 1e-5f);
    ushort8 o;
#pragma unroll
    for (int i = 0; i < 8; ++i) {
        float y = (v[i] - mean) * rs * g[lane * 8 + i] + bta[lane * 8 + i];
        o[i] = f2bf(y);
    }
    *(ushort8*)&outp[(size_t)row * DM + lane * 8] = o;
}

// ---- flash attention v7: 4 KV-chunks of 512 keys, grid 1024,
//      32 q-rows per wave (2 slices share each K/V LDS read) ----
__global__ __launch_bounds__(256, 4) void attn_split(const u16* __restrict__ qkvt,
                                                     u16* __restrict__ po,
                                                     float* __restrict__ pl) {
    __shared__ __align__(16) u16 Ks[64][72];
    __shared__ __align__(16) u16 Vs[64][72];
    int tid = threadIdx.x;
    int lane = tid & 63, wid = tid >> 6;
    int bid = blockIdx.x;
    int cc = bid & 3, qb = (bid >> 2) & 15, hh = (bid >> 6) & 7, b = bid >> 9;
    int fr = lane & 15, kq = (lane >> 4) * 8, rq = (lane >> 4) * 4;

    bf16x8 aq[2][2];
#pragma unroll
    for (int s = 0; s < 2; ++s)
#pragma unroll
        for (int kc = 0; kc < 2; ++kc) {
            int qrow = qb * 128 + wid * 32 + s * 16 + fr;
            bf16x8 t = ldbf8(&qkvt[((size_t)(b * TN + qrow)) * 2048 + hh * 64 + kc * 32 + kq]);
            bf16x8 sc;
#pragma unroll
            for (int i = 0; i < 8; ++i) sc[i] = (__bf16)(0.125f * (float)t[i]);
            aq[s][kc] = sc;
        }

    f32x4 o[2][4] = {};
    float rsum[2] = {0.f, 0.f};

    int srow = tid >> 3, scol = (tid & 7) * 8;
    int vxw = ((scol >> 3) & 7) << 3;
    int i01 = (fr + ((lane & 16) << 1)) << 2;
    int i23 = i01 + 64;
    bool hi2 = (lane & 32) != 0;

    const u16* kvbase = qkvt + ((size_t)(b * TN + cc * 512 + srow)) * 2048 + hh * 64 + scol;

    ushort8 rk[2], rv[2];
    rk[0] = *(const ushort8*)(kvbase + 512);
    rk[1] = *(const ushort8*)(kvbase + 512 + (size_t)32 * 2048);
    rv[0] = *(const ushort8*)(kvbase + 1024);
    rv[1] = *(const ushort8*)(kvbase + 1024 + (size_t)32 * 2048);

    for (int t = 0; t < 8; ++t) {
        __syncthreads();
#pragma unroll
        for (int half = 0; half < 2; ++half) {
            int jr = srow + half * 32;
            *(ushort8*)&Ks[jr][scol] = rk[half];
            int jc = jr ^ vxw;
#pragma unroll
            for (int i = 0; i < 8; ++i) Vs[scol + i][jc] = rv[half][i];
        }
        __syncthreads();
        if (t < 7) {
            const u16* kb2 = kvbase + (size_t)(t + 1) * 64 * 2048;
            rk[0] = *(const ushort8*)(kb2 + 512);
            rk[1] = *(const ushort8*)(kb2 + 512 + (size_t)32 * 2048);
            rv[0] = *(const ushort8*)(kb2 + 1024);
            rv[1] = *(const ushort8*)(kb2 + 1024 + (size_t)32 * 2048);
        }
        u32 pkr[2][4][2];
#pragma unroll
        for (int jb = 0; jb < 4; ++jb) {
            f32x4 sa0 = f32x4{0.f, 0.f, 0.f, 0.f};
            f32x4 sa1 = f32x4{0.f, 0.f, 0.f, 0.f};
#pragma unroll
            for (int kc = 0; kc < 2; ++kc) {
                bf16x8 bk = ldbf8(&Ks[jb * 16 + fr][kc * 32 + kq]);
                sa0 = __builtin_amdgcn_mfma_f32_16x16x32_bf16(bk, aq[0][kc], sa0, 0, 0, 0);
                sa1 = __builtin_amdgcn_mfma_f32_16x16x32_bf16(bk, aq[1][kc], sa1, 0, 0, 0);
            }
            {
                float p0 = __expf(sa0[0]), p1 = __expf(sa0[1]);
                float p2 = __expf(sa0[2]), p3 = __expf(sa0[3]);
                rsum[0] += (p0 + p1) + (p2 + p3);
                pkr[0][jb][0] = ((u32)f2bf(p1) << 16) | (u32)f2bf(p0);
                pkr[0][jb][1] = ((u32)f2bf(p3) << 16) | (u32)f2bf(p2);
            }
            {
                float p0 = __expf(sa1[0]), p1 = __expf(sa1[1]);
                float p2 = __expf(sa1[2]), p3 = __expf(sa1[3]);
                rsum[1] += (p0 + p1) + (p2 + p3);
                pkr[1][jb][0] = ((u32)f2bf(p1) << 16) | (u32)f2bf(p0);
                pkr[1][jb][1] = ((u32)f2bf(p3) << 16) | (u32)f2bf(p2);
            }
        }
        bf16x8 pa[2][2];
#pragma unroll
        for (int s = 0; s < 2; ++s)
#pragma unroll
            for (int kc = 0; kc < 2; ++kc) {
                u32 a0 = (u32)__builtin_amdgcn_ds_bpermute(i01, (int)pkr[s][kc * 2][0]);
                u32 b0 = (u32)__builtin_amdgcn_ds_bpermute(i01, (int)pkr[s][kc * 2 + 1][0]);
                u32 a1 = (u32)__builtin_amdgcn_ds_bpermute(i01, (int)pkr[s][kc * 2][1]);
                u32 b1 = (u32)__builtin_amdgcn_ds_bpermute(i01, (int)pkr[s][kc * 2 + 1][1]);
                u32 a2 = (u32)__builtin_amdgcn_ds_bpermute(i23, (int)pkr[s][kc * 2][0]);
                u32 b2 = (u32)__builtin_amdgcn_ds_bpermute(i23, (int)pkr[s][kc * 2 + 1][0]);
                u32 a3 = (u32)__builtin_amdgcn_ds_bpermute(i23, (int)pkr[s][kc * 2][1]);
                u32 b3 = (u32)__builtin_amdgcn_ds_bpermute(i23, (int)pkr[s][kc * 2 + 1][1]);
                u32x4 w;
                w[0] = hi2 ? b0 : a0;
                w[1] = hi2 ? b1 : a1;
                w[2] = hi2 ? b2 : a2;
                w[3] = hi2 ? b3 : a3;
                pa[s][kc] = __builtin_bit_cast(bf16x8, w);
            }
#pragma unroll
        for (int cb = 0; cb < 4; ++cb)
#pragma unroll
            for (int kc = 0; kc < 2; ++kc) {
                int vrow = cb * 16 + fr;
                bf16x8 bv = ldbf8(&Vs[vrow][(kc * 32 + kq) ^ (((vrow >> 3) & 7) << 3)]);
                o[0][cb] = __builtin_amdgcn_mfma_f32_16x16x32_bf16(pa[0][kc], bv, o[0][cb], 0, 0, 0);
                o[1][cb] = __builtin_amdgcn_mfma_f32_16x16x32_bf16(pa[1][kc], bv, o[1][cb], 0, 0, 0);
            }
    }
#pragma unroll
    for (int s = 0; s < 2; ++s) {
        rsum[s] += __shfl_xor(rsum[s], 16, 64);
        rsum[s] += __shfl_xor(rsum[s], 32, 64);
    }
#pragma unroll
    for (int s = 0; s < 2; ++s)
#pragma unroll
        for (int r = 0; r < 4; ++r) {
            int grow = (b * NHD + hh) * TN + qb * 128 + wid * 32 + s * 16 + rq + r;
            size_t pidx = (size_t)grow * 4 + cc;
#pragma unroll
            for (int cb = 0; cb < 4; ++cb)
                po[pidx * 64 + cb * 16 + fr] = f2bf(o[s][cb][r]);
        }
    if (lane < 16) {
#pragma unroll
        for (int s = 0; s < 2; ++s) {
            int grow = (b * NHD + hh) * TN + qb * 128 + wid * 32 + s * 16 + fr;
            pl[(size_t)grow * 4 + cc] = rsum[s];
        }
    }
}

// ---- merged post-attention: combine 4 partials (blocks 0..2047) + decay scan ----
#define BCH 32
__global__ __launch_bounds__(256) void postattn_kernel(const u16* __restrict__ po,
                                                       const float* __restrict__ pl,
                                                       const u16* __restrict__ qkvt,
                                                       const float* __restrict__ sinv,
                                                       u16* __restrict__ attcat) {
    int bid = blockIdx.x;
    if (bid < BN * NHD * TN / 4) {
        int lane = threadIdx.x & 63, wid = threadIdx.x >> 6;
        int R = bid * 4 + wid;
        float l = 0.f, ov = 0.f;
#pragma unroll
        for (int cc = 0; cc < 4; ++cc) {
            l += pl[(size_t)R * 4 + cc];
            ov += bf2f(po[((size_t)R * 4 + cc) * 64 + lane]);
        }
        int bh = R >> 11, q = R & (TN - 1);
        int b = bh >> 3, hh = bh & 7;
        attcat[((size_t)(b * TN + q)) * 1024 + hh * 128 + lane] = f2bf(ov / l);
    } else {
        int t2 = (bid - BN * NHD * TN / 4) * 256 + threadIdx.x;
        int c = t2 & 511;
        int rest = t2 >> 9;
        int chunk = rest & 63;
        int b = rest >> 6;
        int i0 = chunk * BCH;
        const float r = R_DECAY;
        const u16* tcol = qkvt + 1536 + c;
        float regs[BCH];
        float st = 0.f;
        for (int j = i0 - 32; j < i0; ++j) {
            if (j >= 0) st = r * st + sinv[j] * bf2f(tcol[(size_t)(b * TN + j) * 2048]);
        }
#pragma unroll
        for (int k = 0; k < BCH; ++k) {
            int j = i0 + k;
            st = r * st + sinv[j] * bf2f(tcol[(size_t)(b * TN + j) * 2048]);
            regs[k] = st;
        }
        st = 0.f;
        for (int j = i0 + BCH + 31; j >= i0 + BCH; --j) {
            if (j < TN) st = r * st + sinv[j] * bf2f(tcol[(size_t)(b * TN + j) * 2048]);
        }
#pragma unroll
        for (int k = BCH - 1; k >= 0; --k) {
            int j = i0 + k;
            regs[k] += r * st;
            st = r * st + sinv[j] * bf2f(tcol[(size_t)(b * TN + j) * 2048]);
        }
        int outcol = (c >> 6) * 128 + 64 + (c & 63);
#pragma unroll
        for (int k = 0; k < BCH; ++k)
            attcat[((size_t)(b * TN + i0 + k)) * 1024 + outcol] = f2bf(regs[k]);
    }
}

// ---- fused head ----
__global__ __launch_bounds__(256) void head_kernel(
    const float* __restrict__ h, const float* __restrict__ h1w, const float* __restrict__ h1b,
    const float* __restrict__ bn1g, const float* __restrict__ bn1b,
    const float* __restrict__ bn1m, const float* __restrict__ bn1v,
    const float* __restrict__ h2w, const float* __restrict__ h2b,
    const float* __restrict__ bn2g, const float* __restrict__ bn2b,
    const float* __restrict__ bn2m, const float* __restrict__ bn2v,
    const float* __restrict__ h3w, const float* __restrict__ h3b,
    float* __restrict__ outp) {
    int lane = threadIdx.x & 63, wid = threadIdx.x >> 6;
    int idx = blockIdx.x * 4 + wid;
    const float4* xp = (const float4*)(h + (size_t)idx * DM + lane * 8);
    float4 v0 = xp[0], v1 = xp[1];
    float v[8] = {v0.x, v0.y, v0.z, v0.w, v1.x, v1.y, v1.z, v1.w};
    float a1[32];
#pragma unroll
    for (int o = 0; o < 32; ++o) {
        const float4* wp = (const float4*)(h1w + (size_t)o * DM + lane * 8);
        float4 w0 = wp[0], w1v = wp[1];
        a1[o] = w0.x * v[0] + w0.y * v[1] + w0.z * v[2] + w0.w * v[3] +
                w1v.x * v[4] + w1v.y * v[5] + w1v.z * v[6] + w1v.w * v[7];
    }
    for (int sft = 1; sft < 64; sft <<= 1) {
#pragma unroll
        for (int o = 0; o < 32; ++o) a1[o] += __shfl_xor(a1[o], sft, 64);
    }
    float r1[32];
#pragma unroll
    for (int o = 0; o < 32; ++o) {
        float f = a1[o] + h1b[o];
        f = (f - bn1m[o]) * rsqrtf(bn1v[o] + 1e-5f) * bn1g[o] + bn1b[o];
        r1[o] = fmaxf(f, 0.f);
    }
    float r2[16];
#pragma unroll
    for (int p = 0; p < 16; ++p) {
        float s = h2b[p];
#pragma unroll
        for (int o = 0; o < 32; ++o) s = fmaf(h2w[p * 32 + o], r1[o], s);
        s = (s - bn2m[p]) * rsqrtf(bn2v[p] + 1e-5f) * bn2g[p] + bn2b[p];
        r2[p] = fmaxf(s, 0.f);
    }
    float f3 = h3b[0];
#pragma unroll
    for (int p = 0; p < 16; ++p) f3 = fmaf(h3w[p], r2[p], f3);
    if (lane == 0) outp[idx] = 1.f / (1.f + __expf(-f3));
}

extern "C" void kernel_launch(void* const* d_in, const int* in_sizes, int n_in,
                              void* d_out, int out_size, void* d_ws, size_t ws_size,
                              hipStream_t stream) {
    const float* x     = (const float*)d_in[0];
    const float* emb_w = (const float*)d_in[1];
    const float* emb_b = (const float*)d_in[2];
    const float* ln1_g = (const float*)d_in[3];
    const float* ln1_b = (const float*)d_in[4];
    const float* wqkvt = (const float*)d_in[5];
    const float* wout  = (const float*)d_in[6];
    const float* bout  = (const float*)d_in[7];
    const float* ln2_g = (const float*)d_in[8];
    const float* ln2_b = (const float*)d_in[9];
    const float* w1    = (const float*)d_in[10];
    const float* b1    = (const float*)d_in[11];
    const float* w2    = (const float*)d_in[12];
    const float* b2    = (const float*)d_in[13];
    const float* h1w   = (const float*)d_in[14];
    const float* h1b   = (const float*)d_in[15];
    const float* bn1g  = (const float*)d_in[16];
    const float* bn1b  = (const float*)d_in[17];
    const float* bn1m  = (const float*)d_in[18];
    const float* bn1v  = (const float*)d_in[19];
    const float* h2w   = (const float*)d_in[20];
    const float* h2b   = (const float*)d_in[21];
    const float* bn2g  = (const float*)d_in[22];
    const float* bn2b  = (const float*)d_in[23];
    const float* bn2m  = (const float*)d_in[24];
    const float* bn2v  = (const float*)d_in[25];
    const float* h3w   = (const float*)d_in[26];
    const float* h3b   = (const float*)d_in[27];
    float* outp = (float*)d_out;

    char* ws = (char*)d_ws;
    size_t off = 0;
    auto take = [&](size_t bytes) {
        char* p = ws + off;
        off = (off + bytes + 255) & ~(size_t)255;
        return p;
    };
    const size_t MB = 1024 * 1024;
    float* h    = (float*)take((size_t)BN * TN * DM * 4);   // 8 MB
    char* Pr    = take(18 * MB);                             // union: {xln,z1} | {pl,po}
    u16* attcat = (u16*)take((size_t)BN * TN * 1024 * 2);   // 8 MB
    float* sinv = (float*)take(TN * 4);
    u16* embwt  = (u16*)take((size_t)DM * 3 * DF * 2);
    u16* wqt    = (u16*)take((size_t)2 * 2048 * DM * 2);
    u16* woutt  = (u16*)take((size_t)2 * DM * 1024 * 2);
    u16* w1t    = (u16*)take((size_t)2 * DM * DM * 2);
    u16* w2t    = (u16*)take((size_t)2 * DM * DM * 2);
    u16* qkvtb  = (u16*)take((size_t)BN * TN * 2048 * 2);   // 16 MB
    // phase-disjoint aliases inside Pr:
    u16* xln  = (u16*)Pr;             // 4 MB (LN phase; dead during attention)
    u16* z1   = (u16*)(Pr + 4 * MB);  // 4 MB (MLP phase; po dead then)
    float* pl = (float*)Pr;           // 512 KB (attention phase only)
    u16* po   = (u16*)(Pr + 1 * MB);  // 16.8 MB (attention phase only)
    (void)ws_size; (void)in_sizes; (void)n_in; (void)out_size;

    emb_tr_kernel<<<dim3(DM * 3 * DF / 256), dim3(256), 0, stream>>>(emb_w, embwt, sinv);
    {
        WtrAll a;
        int cur = 0;
        for (int l = 0; l < 2; ++l) {
            int e = l * 4;
            a.src[e + 0] = wqkvt + (size_t)l * 512 * 2048; a.dst[e + 0] = wqt + (size_t)l * 2048 * 512;
            a.K[e + 0] = 512;  a.N[e + 0] = 2048; a.start[e + 0] = cur; a.mask[e + 0] = 31; a.shift[e + 0] = 5; cur += 256;
            a.src[e + 1] = wout + (size_t)l * 1024 * 512;  a.dst[e + 1] = woutt + (size_t)l * 512 * 1024;
            a.K[e + 1] = 1024; a.N[e + 1] = 512;  a.start[e + 1] = cur; a.mask[e + 1] = 7;  a.shift[e + 1] = 3; cur += 128;
            a.src[e + 2] = w1 + (size_t)l * 512 * 512;     a.dst[e + 2] = w1t + (size_t)l * 512 * 512;
            a.K[e + 2] = 512;  a.N[e + 2] = 512;  a.start[e + 2] = cur; a.mask[e + 2] = 7;  a.shift[e + 2] = 3; cur += 64;
            a.src[e + 3] = w2 + (size_t)l * 512 * 512;     a.dst[e + 3] = w2t + (size_t)l * 512 * 512;
            a.K[e + 3] = 512;  a.N[e + 3] = 512;  a.start[e + 3] = cur; a.mask[e + 3] = 7;  a.shift[e + 3] = 3; cur += 64;
        }
        wtr_all_kernel<<<dim3(cur), dim3(256), 0, stream>>>(a);
    }

    // conv-as-GEMM straight from x (tap-shifted f32 staging), 64x64, XCD-chunked
    gemm2<19, 64, 64, 3, 1><<<dim3((DM / 64) * (BN * TN / 64)), dim3(256), 0, stream>>>(
        (const u16*)x, embwt, emb_b, nullptr, h, BN * TN, DM, 3 * DF);

    for (int l = 0; l < 2; ++l) {
        ln_kernel<<<dim3(BN * TN / 4), dim3(256), 0, stream>>>(h, ln1_g + l * DM, ln1_b + l * DM, xln);
        gemm2<0, 128, 128, 4, 0><<<dim3((2048 / 128) * (BN * TN / 128)), dim3(256), 0, stream>>>(
            xln, wqt + (size_t)l * 2048 * 512, nullptr, nullptr, qkvtb, BN * TN, 2048, DM);
        attn_split<<<dim3(BN * NHD * (TN / 128) * 4), dim3(256), 0, stream>>>(qkvtb, po, pl);
        postattn_kernel<<<dim3(BN * NHD * TN / 4 + BN * 512 * (TN / BCH) / 256), dim3(256), 0, stream>>>(
            po, pl, qkvtb, sinv, attcat);
        gemm2<25, 64, 64, 3, 0><<<dim3((DM / 64) * (BN * TN / 64)), dim3(256), 0, stream>>>(
            attcat, woutt + (size_t)l * 512 * 1024, bout + l * DM, h, h, BN * TN, DM, 1024);
        ln_kernel<<<dim3(BN * TN / 4), dim3(256), 0, stream>>>(h, ln2_g + l * DM, ln2_b + l * DM, xln);
        gemm2<5, 64, 64, 3, 0><<<dim3((DM / 64) * (BN * TN / 64)), dim3(256), 0, stream>>>(
            xln, w1t + (size_t)l * 512 * 512, b1 + l * DM, nullptr, z1, BN * TN, DM, DM);
        gemm2<25, 64, 64, 3, 0><<<dim3((DM / 64) * (BN * TN / 64)), dim3(256), 0, stream>>>(
            z1, w2t + (size_t)l * 512 * 512, b2 + l * DM, h, h, BN * TN, DM, DM);
    }
    head_kernel<<<dim3(BN * TN / 4), dim3(256), 0, stream>>>(
        h, h1w, h1b, bn1g, bn1b, bn1m, bn1v, h2w, h2b, bn2g, bn2b, bn2m, bn2v, h3w, h3b, outp);
}